// Round 8
// baseline (670.092 us; speedup 1.0000x reference)
//
#include <hip/hip_runtime.h>
#include <math.h>

typedef unsigned short ushort_t;
typedef __attribute__((ext_vector_type(8))) unsigned short ushortx8;
typedef __attribute__((ext_vector_type(4))) float floatx4;
typedef __attribute__((ext_vector_type(8))) short frag8;   // MFMA A/B operand (8 bf16)

__device__ __forceinline__ float bf2f(ushort_t u){
  union {unsigned int i; float f;} v; v.i = ((unsigned int)u)<<16; return v.f;
}
__device__ __forceinline__ ushort_t f2bf(float f){
  union {float f; unsigned int i;} v; v.f = f;
  unsigned int x = v.i;
  unsigned int r = x + 0x7fffu + ((x>>16)&1u);
  return (ushort_t)(r>>16);
}

__device__ __forceinline__ void gload16(const void* g, void* l){
  __builtin_amdgcn_global_load_lds(
      (const __attribute__((address_space(1))) unsigned int*)g,
      (__attribute__((address_space(3))) unsigned int*)l, 16, 0, 0);
}

// ---------------- CSR build ----------------
__global__ __launch_bounds__(256) void k_count(const int* __restrict__ col, int* __restrict__ cnt, int E){
  int e = blockIdx.x*256 + threadIdx.x;
  if (e < E) atomicAdd(&cnt[col[e]], 1);
}

__global__ __launch_bounds__(256) void k_scan1(const int* __restrict__ cnt, int* __restrict__ offs,
                                               int* __restrict__ partials, int n){
  __shared__ int buf[256];
  int tid = threadIdx.x;
  int gid = blockIdx.x*256 + tid;
  int v = (gid < n) ? cnt[gid] : 0;
  buf[tid] = v; __syncthreads();
  #pragma unroll
  for (int off=1; off<256; off<<=1){
    int t = (tid >= off) ? buf[tid-off] : 0;
    __syncthreads();
    buf[tid] += t;
    __syncthreads();
  }
  if (gid < n) offs[gid] = buf[tid] - v;
  if (tid == 255) partials[blockIdx.x] = buf[255];
}

__global__ __launch_bounds__(256) void k_scan2(int* __restrict__ partials, int nb){
  __shared__ int buf[256];
  int tid = threadIdx.x;
  int v = (tid < nb) ? partials[tid] : 0;
  buf[tid] = v; __syncthreads();
  #pragma unroll
  for (int off=1; off<256; off<<=1){
    int t = (tid >= off) ? buf[tid-off] : 0;
    __syncthreads();
    buf[tid] += t;
    __syncthreads();
  }
  partials[tid] = buf[tid] - v;
}

__global__ __launch_bounds__(256) void k_scan3(int* __restrict__ offs, const int* __restrict__ partials,
                                               int n, int E){
  int gid = blockIdx.x*256 + threadIdx.x;
  if (gid < n) offs[gid] += partials[blockIdx.x];
  if (blockIdx.x == 0 && threadIdx.x == 0) offs[n] = E;
}

__global__ __launch_bounds__(256) void k_fill(const int* __restrict__ row, const int* __restrict__ col,
                                              const int* __restrict__ offs, int* __restrict__ fill,
                                              int* __restrict__ rowS, int E){
  int e = blockIdx.x*256 + threadIdx.x;
  if (e >= E) return;
  int c = col[e];
  int pos = offs[c] + atomicAdd(&fill[c], 1);
  rowS[pos] = row[e];
}

// ---------------- weight conversions ----------------
template<int K, int NC, int CNT>
__global__ __launch_bounds__(256) void k_convT_b(const float* __restrict__ src, ushort_t* __restrict__ dst){
  int idx = blockIdx.x*256 + threadIdx.x;
  if (idx >= CNT*K*NC) return;
  int l = idx / (K*NC);
  int rem = idx - l*(K*NC);
  int k = rem / NC, n = rem - k*NC;
  dst[(size_t)l*K*NC + (size_t)n*K + k] = f2bf(src[idx]);
}

__global__ __launch_bounds__(256) void k_convT4(const float* __restrict__ s0, const float* __restrict__ s1,
                                                const float* __restrict__ s2, const float* __restrict__ s3,
                                                ushort_t* __restrict__ d0, ushort_t* __restrict__ d1,
                                                ushort_t* __restrict__ d2, ushort_t* __restrict__ d3){
  int idx = blockIdx.x*256 + threadIdx.x;
  if (idx >= 4*16384) return;
  int which = idx >> 14;
  int rem = idx & 16383;
  int k = rem >> 7, n = rem & 127;
  const float* s = which==0 ? s0 : which==1 ? s1 : which==2 ? s2 : s3;
  ushort_t*    d = which==0 ? d0 : which==1 ? d1 : which==2 ? d2 : d3;
  d[n*128 + k] = f2bf(s[rem]);
}

// ---------------- fused dense building blocks ----------------
// Tiles are XOR-swizzled at 16B granularity: logical (row, col-group cg) lives
// at chunk row*CW + (cg ^ (row&7)). Involution; staged via pre-swizzled SOURCE.

__device__ __forceinline__ void la_store(ushort_t* LA, int row, int col, ushort_t v){
  LA[row*128 + ((((col>>3) ^ (row&7))<<3) | (col&7))] = v;
}
__device__ __forceinline__ void la_store8(ushort_t* LA, int row, int cg, ushortx8 v){
  *(ushortx8*)&LA[row*128 + ((cg ^ (row&7))<<3)] = v;
}

// stage [128 rows][64 k] bf16 tile from row-major global into swizzled LDS tile (CW=8)
__device__ __forceinline__ void stage64_swz(const ushort_t* __restrict__ src, int ld, int row0, int M,
                                            int kc, ushort_t* lds, int tid){
  #pragma unroll
  for (int i=0;i<4;i++){
    int chunk = tid + 256*i;          // 0..1023 16B chunks
    int r = chunk>>3, cg = chunk&7;
    int gr = row0 + r; if (gr >= M) gr = M-1;
    int scg = cg ^ (r&7);
    gload16(src + (size_t)gr*ld + kc + scg*8, (char*)lds + (size_t)chunk*16);
  }
}

// acc += A[128 rows][64k slice @kaoff of CWA*8-wide tile] * B[128][64]^T (both swizzled)
template<int CWA>
__device__ __forceinline__ void ldsgemm64(const ushort_t* LA, int kaoff, const ushort_t* LB,
                                          floatx4 (&acc)[4][4], int wr,int wc,int lm,int lk){
  #pragma unroll
  for (int ks=0; ks<2; ks++){
    frag8 a[4], b[4];
    int cga = (kaoff + ks*32 + lk) >> 3;
    #pragma unroll
    for (int mi=0;mi<4;mi++){
      int row = wr + mi*16 + lm;
      a[mi] = *(const frag8*)&LA[row*(CWA*8) + ((cga ^ (row&7))<<3)];
    }
    int cgb = (ks*32 + lk) >> 3;
    #pragma unroll
    for (int ni=0;ni<4;ni++){
      int row = wc + ni*16 + lm;
      b[ni] = *(const frag8*)&LB[row*64 + ((cgb ^ (row&7))<<3)];
    }
    #pragma unroll
    for (int mi=0;mi<4;mi++)
      #pragma unroll
      for (int ni=0;ni<4;ni++)
        acc[mi][ni] = __builtin_amdgcn_mfma_f32_16x16x32_bf16(a[mi], b[ni], acc[mi][ni], 0, 0, 0);
  }
}

__device__ __forceinline__ void zero_acc(floatx4 (&acc)[4][4]){
  #pragma unroll
  for (int i=0;i<4;i++)
    #pragma unroll
    for (int j=0;j<4;j++) acc[i][j] = floatx4{0.f,0.f,0.f,0.f};
}

// per-head W-GEMM for 2 heads (hb = by*2 + hh) + h write + sdst partials; combined write at end.
// LA holds swizzled x_bf16 [128][128]; LB is the [128][64] staging buffer; sred = float[1024].
__device__ __forceinline__ void wgemm_2heads(const ushort_t* LA, ushort_t* LB,
    const ushort_t* __restrict__ WT, const float* __restrict__ avec_s, const float* __restrict__ avec_d,
    ushort_t* __restrict__ h, float* __restrict__ s_src, float* __restrict__ s_dst, float* sred,
    int by, int bm, int M, int tid, int wid, int lane, int wr, int wc, int lm, int lk, int lr4){
  for (int hh=0; hh<2; hh++){
    int hb = by*2 + hh;
    floatx4 acc[4][4]; zero_acc(acc);
    #pragma unroll
    for (int kph=0; kph<2; kph++){
      stage64_swz(WT + (size_t)hb*16384, 128, 0, 128, kph*64, LB, tid);
      __syncthreads();
      ldsgemm64<16>(LA, kph*64, LB, acc, wr, wc, lm, lk);
      __syncthreads();
    }
    // h write
    #pragma unroll
    for (int mi=0;mi<4;mi++)
      #pragma unroll
      for (int ni=0;ni<4;ni++){
        int colg = wc + ni*16 + lm;
        #pragma unroll
        for (int r=0;r<4;r++){
          int rowg = bm + wr + mi*16 + lr4 + r;
          if (rowg < M) h[(size_t)rowg*512 + hb*128 + colg] = f2bf(acc[mi][ni][r]);
        }
      }
    // sdst partials -> disjoint sred region [hh][sd][half][128]
    float avs[4], avd[4];
    #pragma unroll
    for (int ni=0;ni<4;ni++){
      int d = wc + ni*16 + lm;
      avs[ni] = avec_s[hb*128 + d];
      avd[ni] = avec_d[hb*128 + d];
    }
    #pragma unroll
    for (int mi=0;mi<4;mi++){
      #pragma unroll
      for (int r=0;r<4;r++){
        float vs = 0.f, vd = 0.f;
        #pragma unroll
        for (int ni=0;ni<4;ni++){
          float v = acc[mi][ni][r];
          vs += v * avs[ni];
          vd += v * avd[ni];
        }
        #pragma unroll
        for (int m=1;m<16;m<<=1){
          vs += __shfl_xor(vs, m);
          vd += __shfl_xor(vd, m);
        }
        if (lm == 0){
          int rl = wr + mi*16 + lr4 + r;
          int half = wid & 1;
          sred[((hh*2+0)*2 + half)*128 + rl] = vs;
          sred[((hh*2+1)*2 + half)*128 + rl] = vd;
        }
      }
    }
  }
  __syncthreads();
  // combined sdst write: 512 slots (hh, sd, rl)
  for (int q = tid; q < 512; q += 256){
    int hh = q >> 8, sd = (q >> 7) & 1, rl = q & 127;
    float v = sred[((hh*2+sd)*2+0)*128 + rl] + sred[((hh*2+sd)*2+1)*128 + rl];
    int rowg = bm + rl;
    if (rowg < M) (sd ? s_dst : s_src)[(size_t)rowg*4 + by*2 + hh] = v;
  }
}

// ---------------- k_enc: conv + enc1(relu) + enc2 -> xA ; + WGEMM layer0 (2 heads) + SDST ----------------
__global__ __launch_bounds__(256,3) void k_enc(
    const float* __restrict__ nodef,
    const ushort_t* __restrict__ e1T, const float* __restrict__ eb1,
    const ushort_t* __restrict__ e2T, const float* __restrict__ eb2,
    const ushort_t* __restrict__ WT, const float* __restrict__ avs, const float* __restrict__ avd,
    float* __restrict__ xout, ushort_t* __restrict__ h,
    float* __restrict__ s_src, float* __restrict__ s_dst, int M)
{
  __shared__ ushort_t LA[128*128];
  __shared__ ushort_t LB[128*64];
  __shared__ float sred[1024];
  const int tid = threadIdx.x, wid = tid>>6, lane = tid&63;
  const int bm = blockIdx.x*128, by = blockIdx.y;
  const int wr = (wid>>1)*64, wc = (wid&1)*64, lm = lane&15, lk = (lane>>4)*8, lr4 = (lane>>4)*4;

  // stage node features (f32 -> bf16) into swizzled LA
  #pragma unroll
  for (int i=0;i<8;i++){
    int chunk = tid + 256*i;                 // 0..2047
    int r = chunk>>4, cg = chunk&15;
    int gr = bm + r; if (gr >= M) gr = M-1;
    floatx4 lo = *(const floatx4*)(nodef + (size_t)gr*128 + cg*8);
    floatx4 hi = *(const floatx4*)(nodef + (size_t)gr*128 + cg*8 + 4);
    ushortx8 v;
    #pragma unroll
    for (int j=0;j<4;j++){ v[j] = f2bf(lo[j]); v[j+4] = f2bf(hi[j]); }
    la_store8(LA, r, cg, v);
  }
  __syncthreads();

  floatx4 acc[4][4]; zero_acc(acc);
  #pragma unroll
  for (int kph=0; kph<2; kph++){
    stage64_swz(e1T, 128, 0, 128, kph*64, LB, tid);
    __syncthreads();
    ldsgemm64<16>(LA, kph*64, LB, acc, wr, wc, lm, lk);
    __syncthreads();
  }
  // t1 = relu(acc + eb1) -> LA
  #pragma unroll
  for (int mi=0;mi<4;mi++)
    #pragma unroll
    for (int ni=0;ni<4;ni++){
      int cl = wc + ni*16 + lm;
      float b = eb1[cl];
      #pragma unroll
      for (int r=0;r<4;r++){
        float v = acc[mi][ni][r] + b;
        v = v > 0.f ? v : 0.f;
        la_store(LA, wr + mi*16 + lr4 + r, cl, f2bf(v));
      }
    }
  zero_acc(acc);
  #pragma unroll
  for (int kph=0; kph<2; kph++){
    stage64_swz(e2T, 128, 0, 128, kph*64, LB, tid);
    __syncthreads();
    ldsgemm64<16>(LA, kph*64, LB, acc, wr, wc, lm, lk);
    __syncthreads();
  }
  // x = acc + eb2 -> global f32 (by==0 only) + LA bf16
  #pragma unroll
  for (int mi=0;mi<4;mi++)
    #pragma unroll
    for (int ni=0;ni<4;ni++){
      int cl = wc + ni*16 + lm;
      float b = eb2[cl];
      #pragma unroll
      for (int r=0;r<4;r++){
        int rl = wr + mi*16 + lr4 + r;
        int rowg = bm + rl;
        float v = acc[mi][ni][r] + b;
        if (by == 0 && rowg < M) xout[(size_t)rowg*128 + cl] = v;
        la_store(LA, rl, cl, f2bf(v));
      }
    }

  wgemm_2heads(LA, LB, WT, avs, avd, h, s_src, s_dst, sred,
               by, bm, M, tid, wid, lane, wr, wc, lm, lk, lr4);
}

// ---------------- k_mid: out-proj + bias + resid(xin) -> xout ; + next WGEMM (2 heads) + SDST ----------------
__global__ __launch_bounds__(256,3) void k_mid(
    const ushort_t* __restrict__ msg, const ushort_t* __restrict__ OT, const float* __restrict__ ob,
    const ushort_t* __restrict__ WT, const float* __restrict__ avs, const float* __restrict__ avd,
    const float* __restrict__ xin, float* __restrict__ xout, ushort_t* __restrict__ h,
    float* __restrict__ s_src, float* __restrict__ s_dst, int M)
{
  __shared__ ushort_t LA[128*128];
  __shared__ ushort_t LB[128*64];
  __shared__ float sred[1024];
  const int tid = threadIdx.x, wid = tid>>6, lane = tid&63;
  const int bm = blockIdx.x*128, by = blockIdx.y;
  const int wr = (wid>>1)*64, wc = (wid&1)*64, lm = lane&15, lk = (lane>>4)*8, lr4 = (lane>>4)*4;

  floatx4 acc[4][4]; zero_acc(acc);
  for (int kc = 0; kc < 512; kc += 64){
    stage64_swz(msg, 512, bm, M, kc, LA, tid);   // LA used as CW8 [128][64] tile here
    stage64_swz(OT,  512, 0, 128, kc, LB, tid);
    __syncthreads();
    ldsgemm64<8>(LA, 0, LB, acc, wr, wc, lm, lk);
    __syncthreads();
  }
  // x_new = acc + ob + x_old -> global f32 (by==0) + LA bf16 [128][128]
  #pragma unroll
  for (int mi=0;mi<4;mi++)
    #pragma unroll
    for (int ni=0;ni<4;ni++){
      int cl = wc + ni*16 + lm;
      float b = ob[cl];
      #pragma unroll
      for (int r=0;r<4;r++){
        int rl = wr + mi*16 + lr4 + r;
        int rowg = bm + rl;
        float v = acc[mi][ni][r] + b;
        if (rowg < M){
          v += xin[(size_t)rowg*128 + cl];
          if (by == 0) xout[(size_t)rowg*128 + cl] = v;
        }
        la_store(LA, rl, cl, f2bf(v));
      }
    }

  wgemm_2heads(LA, LB, WT, avs, avd, h, s_src, s_dst, sred,
               by, bm, M, tid, wid, lane, wr, wc, lm, lk, lr4);
}

// ---------------- k_tail: out-proj3 + resid -> MLP1(relu) -> MLP2 -> d_out + colsum ----------------
__global__ __launch_bounds__(256,3) void k_tail(
    const ushort_t* __restrict__ msg, const ushort_t* __restrict__ OT, const float* __restrict__ ob,
    const ushort_t* __restrict__ m1T, const float* __restrict__ mb1,
    const ushort_t* __restrict__ m2T, const float* __restrict__ mb2,
    const float* __restrict__ xin, float* __restrict__ out, float* __restrict__ cpart, int M)
{
  __shared__ ushort_t LA[128*128];
  __shared__ ushort_t LB[128*64];
  __shared__ float sred[1024];
  const int tid = threadIdx.x, wid = tid>>6, lane = tid&63;
  const int bm = blockIdx.x*128;
  const int wr = (wid>>1)*64, wc = (wid&1)*64, lm = lane&15, lk = (lane>>4)*8, lr4 = (lane>>4)*4;

  floatx4 acc[4][4]; zero_acc(acc);
  for (int kc = 0; kc < 512; kc += 64){
    stage64_swz(msg, 512, bm, M, kc, LA, tid);
    stage64_swz(OT,  512, 0, 128, kc, LB, tid);
    __syncthreads();
    ldsgemm64<8>(LA, 0, LB, acc, wr, wc, lm, lk);
    __syncthreads();
  }
  // x3 = acc + ob + x_old -> LA bf16
  #pragma unroll
  for (int mi=0;mi<4;mi++)
    #pragma unroll
    for (int ni=0;ni<4;ni++){
      int cl = wc + ni*16 + lm;
      float b = ob[cl];
      #pragma unroll
      for (int r=0;r<4;r++){
        int rl = wr + mi*16 + lr4 + r;
        int rowg = bm + rl;
        float v = acc[mi][ni][r] + b;
        if (rowg < M) v += xin[(size_t)rowg*128 + cl];
        la_store(LA, rl, cl, f2bf(v));
      }
    }
  zero_acc(acc);
  #pragma unroll
  for (int kph=0; kph<2; kph++){
    stage64_swz(m1T, 128, 0, 128, kph*64, LB, tid);
    __syncthreads();
    ldsgemm64<16>(LA, kph*64, LB, acc, wr, wc, lm, lk);
    __syncthreads();
  }
  // t = relu(acc + mb1) -> LA
  #pragma unroll
  for (int mi=0;mi<4;mi++)
    #pragma unroll
    for (int ni=0;ni<4;ni++){
      int cl = wc + ni*16 + lm;
      float b = mb1[cl];
      #pragma unroll
      for (int r=0;r<4;r++){
        float v = acc[mi][ni][r] + b;
        v = v > 0.f ? v : 0.f;
        la_store(LA, wr + mi*16 + lr4 + r, cl, f2bf(v));
      }
    }
  zero_acc(acc);
  #pragma unroll
  for (int kph=0; kph<2; kph++){
    stage64_swz(m2T, 128, 0, 128, kph*64, LB, tid);
    __syncthreads();
    ldsgemm64<16>(LA, kph*64, LB, acc, wr, wc, lm, lk);
    __syncthreads();
  }
  float csum[4];
  #pragma unroll
  for (int i=0;i<4;i++) csum[i] = 0.f;
  #pragma unroll
  for (int mi=0;mi<4;mi++)
    #pragma unroll
    for (int ni=0;ni<4;ni++){
      int cl = wc + ni*16 + lm;
      float b = mb2[cl];
      #pragma unroll
      for (int r=0;r<4;r++){
        int rowg = bm + wr + mi*16 + lr4 + r;
        if (rowg < M){
          float v = acc[mi][ni][r] + b;
          out[(size_t)rowg*128 + cl] = v;
          csum[ni] += v;
        }
      }
    }
  #pragma unroll
  for (int ni=0;ni<4;ni++){
    float cs = csum[ni];
    cs += __shfl_xor(cs, 16);
    cs += __shfl_xor(cs, 32);
    if (lane < 16) sred[(wid>>1)*128 + wc + ni*16 + lane] = cs;
  }
  __syncthreads();
  if (tid < 128) cpart[(size_t)blockIdx.x*128 + tid] = sred[tid] + sred[128 + tid];
}

// ---------------- fused attention gather (round-5 structure, unchanged) ----------------
__global__ __launch_bounds__(256) void k_gather(const ushort_t* __restrict__ h,
    const float* __restrict__ s_src, const float* __restrict__ s_dst,
    const int* __restrict__ offs, const int* __restrict__ rowS,
    ushort_t* __restrict__ msg, int N)
{
  int wid = threadIdx.x >> 6, lane = threadIdx.x & 63;
  int n = blockIdx.x*4 + wid;
  if (n >= N) return;
  int beg = offs[n], end = offs[n+1];
  const int sub  = lane & 15;
  const int head = lane >> 4;
  const float sdv = s_dst[(size_t)n*4 + head];
  const int c0 = lane*8;

  float acc[8];
  #pragma unroll
  for (int k=0;k<8;k++) acc[k] = 0.f;
  float dsum = 0.f;

  for (int chunk = beg; chunk < end; chunk += 16){
    int m = end - chunk; if (m > 16) m = 16;
    int q = chunk + (sub < m ? sub : m-1);
    int r_p = rowS[q];
    float ss = s_src[(size_t)r_p*4 + head];
    float e = ss + sdv;
    e = e > 0.f ? e : 0.2f*e;
    float w = __expf(e);
    if (sub >= m) w = 0.f;
    dsum += w;

    int j = 0;
    for (; j+1 < m; j += 2){
      int r0 = __shfl(r_p, j);
      int r1 = __shfl(r_p, j+1);
      float w0 = __shfl(w, head*16 + j);
      float w1 = __shfl(w, head*16 + j+1);
      ushortx8 h0 = *(const ushortx8*)(h + (size_t)r0*512 + c0);
      ushortx8 h1 = *(const ushortx8*)(h + (size_t)r1*512 + c0);
      #pragma unroll
      for (int k=0;k<8;k++) acc[k] += w0 * bf2f(h0[k]);
      #pragma unroll
      for (int k=0;k<8;k++) acc[k] += w1 * bf2f(h1[k]);
    }
    if (j < m){
      int r0 = __shfl(r_p, j);
      float w0 = __shfl(w, head*16 + j);
      ushortx8 h0 = *(const ushortx8*)(h + (size_t)r0*512 + c0);
      #pragma unroll
      for (int k=0;k<8;k++) acc[k] += w0 * bf2f(h0[k]);
    }
  }

  float d = dsum;
  #pragma unroll
  for (int mask=1; mask<16; mask<<=1) d += __shfl_xor(d, mask);
  float invd = 1.0f / (d + 1e-8f);

  ushortx8 o;
  #pragma unroll
  for (int k=0;k<8;k++) o[k] = f2bf(acc[k]*invd);
  __builtin_nontemporal_store(o, (ushortx8*)(msg + (size_t)n*512 + c0));
}

// ---------------- reduce per-block column partials -> mean ----------------
__global__ __launch_bounds__(256) void k_csum2(const float* __restrict__ part, float* __restrict__ out,
                                               int nb, int N){
  __shared__ float buf[256];
  int c = threadIdx.x & 127, half = threadIdx.x >> 7;
  float s = 0.f;
  for (int b = half; b < nb; b += 2) s += part[(size_t)b*128 + c];
  buf[threadIdx.x] = s; __syncthreads();
  if (threadIdx.x < 128) out[c] = (buf[c] + buf[128 + c]) / (float)N;
}

extern "C" void kernel_launch(void* const* d_in, const int* in_sizes, int n_in,
                              void* d_out, int out_size, void* d_ws, size_t ws_size,
                              hipStream_t stream)
{
  const int N = in_sizes[0] / 128;
  const int E = in_sizes[1] / 2;

  const float* nodef  = (const float*)d_in[0];
  const int*   row    = (const int*)d_in[1];
  const int*   col    = row + E;
  const float* enc_w1 = (const float*)d_in[2];
  const float* enc_b1 = (const float*)d_in[3];
  const float* enc_w2 = (const float*)d_in[4];
  const float* enc_b2 = (const float*)d_in[5];
  const float* gat_W  = (const float*)d_in[6];
  const float* a_src  = (const float*)d_in[7];
  const float* a_dst  = (const float*)d_in[8];
  const float* out_w  = (const float*)d_in[9];
  const float* out_b  = (const float*)d_in[10];
  const float* w1     = (const float*)d_in[11];
  const float* b1     = (const float*)d_in[12];
  const float* w2     = (const float*)d_in[13];
  const float* b2     = (const float*)d_in[14];

  char* p = (char*)d_ws;
  auto alloc = [&](size_t bytes)->char*{
    char* r = p; p += (bytes + 255) & ~(size_t)255; return r;
  };
  float*    xA    = (float*)   alloc((size_t)N*128*4);
  float*    xB    = (float*)   alloc((size_t)N*128*4);
  ushort_t* msg   = (ushort_t*)alloc((size_t)N*512*2);
  ushort_t* h     = (ushort_t*)alloc((size_t)N*512*2);
  float*    s_src = (float*)   alloc((size_t)N*4*4);
  float*    s_dst = (float*)   alloc((size_t)N*4*4);
  int*      offs  = (int*)     alloc(((size_t)N+1)*4);
  int*      rowS  = (int*)     alloc((size_t)E*4);
  int*      cnt   = (int*)     alloc((size_t)N*4);
  int*      fill  = (int*)     alloc((size_t)N*4);
  int*      parts = (int*)     alloc(1024);
  float*    cpart = (float*)   alloc((size_t)((N+127)/128)*128*4);
  ushort_t* wt_e1 = (ushort_t*)alloc(16384*2);
  ushort_t* wt_e2 = (ushort_t*)alloc(16384*2);
  ushort_t* wt_W  = (ushort_t*)alloc((size_t)3*65536*2);
  ushort_t* wt_o  = (ushort_t*)alloc((size_t)3*65536*2);
  ushort_t* wt_m1 = (ushort_t*)alloc(16384*2);
  ushort_t* wt_m2 = (ushort_t*)alloc(16384*2);

  hipMemsetAsync(cnt, 0, (size_t)N*4, stream);
  hipMemsetAsync(fill, 0, (size_t)N*4, stream);

  const int gE = (E + 255)/256;
  const int gN = (N + 255)/256;
  const int gW = (N + 3)/4;
  const int gy = (N + 127)/128;
  dim3 blk(256);

  // CSR by destination
  k_count<<<gE, blk, 0, stream>>>(col, cnt, E);
  k_scan1<<<gN, blk, 0, stream>>>(cnt, offs, parts, N);
  k_scan2<<<1,  blk, 0, stream>>>(parts, gN);
  k_scan3<<<gN, blk, 0, stream>>>(offs, parts, N, E);
  k_fill <<<gE, blk, 0, stream>>>(row, col, offs, fill, rowS, E);

  // weight conversion (bf16, transposed to [NC,K])
  k_convT4<<<(4*16384+255)/256, blk, 0, stream>>>(enc_w1, enc_w2, w1, w2, wt_e1, wt_e2, wt_m1, wt_m2);
  k_convT_b<128,512,3><<<(3*65536+255)/256, blk, 0, stream>>>(gat_W, wt_W);
  k_convT_b<512,128,3><<<(3*65536+255)/256, blk, 0, stream>>>(out_w, wt_o);

  // encoder + layer-0 W-GEMM + SDST  (2 head-groups per row-block)
  k_enc<<<dim3(gy,2), blk, 0, stream>>>(nodef, wt_e1, enc_b1, wt_e2, enc_b2,
                                        wt_W, a_src, a_dst, xA, h, s_src, s_dst, N);

  // layer 0: gather -> k_mid (reads xA, writes xB, preps layer-1)
  k_gather<<<gW, blk, 0, stream>>>(h, s_src, s_dst, offs, rowS, msg, N);
  k_mid<<<dim3(gy,2), blk, 0, stream>>>(msg, wt_o, out_b,
                                        wt_W + (size_t)1*65536, a_src + 512, a_dst + 512,
                                        xA, xB, h, s_src, s_dst, N);
  // layer 1: gather -> k_mid (reads xB, writes xA, preps layer-2)
  k_gather<<<gW, blk, 0, stream>>>(h, s_src, s_dst, offs, rowS, msg, N);
  k_mid<<<dim3(gy,2), blk, 0, stream>>>(msg, wt_o + (size_t)1*65536, out_b + 128,
                                        wt_W + (size_t)2*65536, a_src + 1024, a_dst + 1024,
                                        xB, xA, h, s_src, s_dst, N);
  // layer 2: gather -> k_tail
  k_gather<<<gW, blk, 0, stream>>>(h, s_src, s_dst, offs, rowS, msg, N);
  k_tail<<<gy, blk, 0, stream>>>(msg, wt_o + (size_t)2*65536, out_b + 256,
                                 wt_m1, b1, wt_m2, b2,
                                 xA, (float*)d_out, cpart, N);

  k_csum2<<<1, blk, 0, stream>>>(cpart, (float*)d_out + (size_t)N*128, gy, N);
}

// Round 9
// 555.153 us; speedup vs baseline: 1.2070x; 1.2070x over previous
//
#include <hip/hip_runtime.h>
#include <math.h>

typedef unsigned short ushort_t;
typedef __attribute__((ext_vector_type(8))) unsigned short ushortx8;
typedef __attribute__((ext_vector_type(4))) float floatx4;
typedef __attribute__((ext_vector_type(8))) short frag8;   // MFMA A/B operand (8 bf16)

__device__ __forceinline__ float bf2f(ushort_t u){
  union {unsigned int i; float f;} v; v.i = ((unsigned int)u)<<16; return v.f;
}
__device__ __forceinline__ ushort_t f2bf(float f){
  union {float f; unsigned int i;} v; v.f = f;
  unsigned int x = v.i;
  unsigned int r = x + 0x7fffu + ((x>>16)&1u);
  return (ushort_t)(r>>16);
}

__device__ __forceinline__ void gload16(const void* g, void* l){
  __builtin_amdgcn_global_load_lds(
      (const __attribute__((address_space(1))) unsigned int*)g,
      (__attribute__((address_space(3))) unsigned int*)l, 16, 0, 0);
}

// ---------------- CSR build ----------------
__global__ __launch_bounds__(256) void k_count(const int* __restrict__ col, int* __restrict__ cnt, int E){
  int e = blockIdx.x*256 + threadIdx.x;
  if (e < E) atomicAdd(&cnt[col[e]], 1);
}

__global__ __launch_bounds__(256) void k_scan1(const int* __restrict__ cnt, int* __restrict__ offs,
                                               int* __restrict__ partials, int n){
  __shared__ int buf[256];
  int tid = threadIdx.x;
  int gid = blockIdx.x*256 + tid;
  int v = (gid < n) ? cnt[gid] : 0;
  buf[tid] = v; __syncthreads();
  #pragma unroll
  for (int off=1; off<256; off<<=1){
    int t = (tid >= off) ? buf[tid-off] : 0;
    __syncthreads();
    buf[tid] += t;
    __syncthreads();
  }
  if (gid < n) offs[gid] = buf[tid] - v;
  if (tid == 255) partials[blockIdx.x] = buf[255];
}

__global__ __launch_bounds__(256) void k_scan2(int* __restrict__ partials, int nb){
  __shared__ int buf[256];
  int tid = threadIdx.x;
  int v = (tid < nb) ? partials[tid] : 0;
  buf[tid] = v; __syncthreads();
  #pragma unroll
  for (int off=1; off<256; off<<=1){
    int t = (tid >= off) ? buf[tid-off] : 0;
    __syncthreads();
    buf[tid] += t;
    __syncthreads();
  }
  partials[tid] = buf[tid] - v;
}

__global__ __launch_bounds__(256) void k_scan3(int* __restrict__ offs, const int* __restrict__ partials,
                                               int n, int E){
  int gid = blockIdx.x*256 + threadIdx.x;
  if (gid < n) offs[gid] += partials[blockIdx.x];
  if (blockIdx.x == 0 && threadIdx.x == 0) offs[n] = E;
}

__global__ __launch_bounds__(256) void k_fill(const int* __restrict__ row, const int* __restrict__ col,
                                              const int* __restrict__ offs, int* __restrict__ fill,
                                              int* __restrict__ rowS, int E){
  int e = blockIdx.x*256 + threadIdx.x;
  if (e >= E) return;
  int c = col[e];
  int pos = offs[c] + atomicAdd(&fill[c], 1);
  rowS[pos] = row[e];
}

// ---------------- weight conversions ----------------
template<int K, int NC, int CNT>
__global__ __launch_bounds__(256) void k_convT_b(const float* __restrict__ src, ushort_t* __restrict__ dst){
  int idx = blockIdx.x*256 + threadIdx.x;
  if (idx >= CNT*K*NC) return;
  int l = idx / (K*NC);
  int rem = idx - l*(K*NC);
  int k = rem / NC, n = rem - k*NC;
  dst[(size_t)l*K*NC + (size_t)n*K + k] = f2bf(src[idx]);
}

__global__ __launch_bounds__(256) void k_convT4(const float* __restrict__ s0, const float* __restrict__ s1,
                                                const float* __restrict__ s2, const float* __restrict__ s3,
                                                ushort_t* __restrict__ d0, ushort_t* __restrict__ d1,
                                                ushort_t* __restrict__ d2, ushort_t* __restrict__ d3){
  int idx = blockIdx.x*256 + threadIdx.x;
  if (idx >= 4*16384) return;
  int which = idx >> 14;
  int rem = idx & 16383;
  int k = rem >> 7, n = rem & 127;
  const float* s = which==0 ? s0 : which==1 ? s1 : which==2 ? s2 : s3;
  ushort_t*    d = which==0 ? d0 : which==1 ? d1 : which==2 ? d2 : d3;
  d[n*128 + k] = f2bf(s[rem]);
}

// ---------------- fused-kernel building blocks (round-6 structure) ----------------
// stage a [128 rows][128 k] bf16 tile from row-major global (ld elems) into lds (stride 128)
__device__ __forceinline__ void stage_tile128(const ushort_t* src, int ld, int row0, int M, int kc,
                                              ushort_t* lds, int tid){
  #pragma unroll
  for (int i=0;i<8;i++){
    int chunk = tid + 256*i;             // 0..2047 (16B chunks)
    int r = chunk>>4, c8 = chunk&15;
    int gr = row0 + r; if (gr >= M) gr = M-1;
    gload16(src + (size_t)gr*ld + kc + c8*8, (char*)lds + (size_t)chunk*16);
  }
}
// stage a full contiguous [128][128] bf16 weight block into lds (stride 128)
__device__ __forceinline__ void stage_w128(const ushort_t* src, ushort_t* lds, int tid){
  #pragma unroll
  for (int i=0;i<8;i++){
    int chunk = tid + 256*i;             // 0..2047
    gload16(src + (size_t)chunk*8, (char*)lds + (size_t)chunk*16);
  }
}

// GEMM on LDS tiles: acc += LA[128xK] * LB[128xK]^T  (strides SA/SB, K = NKS*32)
template<int SA,int SB,int NKS>
__device__ __forceinline__ void ldsgemm(const ushort_t* LA, const ushort_t* LB,
                                        floatx4 (&acc)[4][4], int wr,int wc,int lm,int lk){
  #pragma unroll
  for (int ks=0; ks<NKS; ks++){
    frag8 a[4], b[4];
    #pragma unroll
    for (int mi=0;mi<4;mi++) a[mi] = *(const frag8*)&LA[(wr+mi*16+lm)*SA + ks*32 + lk];
    #pragma unroll
    for (int ni=0;ni<4;ni++) b[ni] = *(const frag8*)&LB[(wc+ni*16+lm)*SB + ks*32 + lk];
    #pragma unroll
    for (int mi=0;mi<4;mi++)
      #pragma unroll
      for (int ni=0;ni<4;ni++)
        acc[mi][ni] = __builtin_amdgcn_mfma_f32_16x16x32_bf16(a[mi], b[ni], acc[mi][ni], 0, 0, 0);
  }
}

__device__ __forceinline__ void zero_acc(floatx4 (&acc)[4][4]){
  #pragma unroll
  for (int i=0;i<4;i++)
    #pragma unroll
    for (int j=0;j<4;j++) acc[i][j] = floatx4{0.f,0.f,0.f,0.f};
}

// s_src/s_dst for one head from the acc block (rows bm..bm+127, head-dims 0..127)
__device__ __forceinline__ void sdst_block(const floatx4 (&acc)[4][4],
    const float* avec_s, const float* avec_d, float* s_src, float* s_dst, float* sred,
    int head, int bm, int M, int tid, int wid, int lane, int wr, int wc, int lm, int lr4){
  float avs[4], avd[4];
  #pragma unroll
  for (int ni=0;ni<4;ni++){
    int d = wc + ni*16 + lm;
    avs[ni] = avec_s[head*128 + d];
    avd[ni] = avec_d[head*128 + d];
  }
  float pss[4][4], psd[4][4];
  #pragma unroll
  for (int mi=0;mi<4;mi++){
    #pragma unroll
    for (int r=0;r<4;r++){
      float vs = 0.f, vd = 0.f;
      #pragma unroll
      for (int ni=0;ni<4;ni++){
        float v = acc[mi][ni][r];
        vs += v * avs[ni];
        vd += v * avd[ni];
      }
      #pragma unroll
      for (int m=1;m<16;m<<=1){
        vs += __shfl_xor(vs, m);
        vd += __shfl_xor(vd, m);
      }
      pss[mi][r] = vs; psd[mi][r] = vd;
    }
  }
  if (lm == 0){
    #pragma unroll
    for (int mi=0;mi<4;mi++)
      #pragma unroll
      for (int r=0;r<4;r++){
        int rl = wr + mi*16 + lr4 + r;
        sred[0*256 + (wid&1)*128 + rl] = pss[mi][r];
        sred[1*256 + (wid&1)*128 + rl] = psd[mi][r];
      }
  }
  __syncthreads();
  int sd = tid >> 7, rl = tid & 127;
  float v = sred[sd*256 + rl] + sred[sd*256 + 128 + rl];
  int rowg = bm + rl;
  if (rowg < M) (sd ? s_dst : s_src)[(size_t)rowg*4 + head] = v;
}

// phase: h = LA(xb,[128][128]) @ WT^T per head + SDST.  LA preserved, LB clobbered.
__device__ __forceinline__ void wgemm_heads(const ushort_t* LA_xb, ushort_t* LB,
    const ushort_t* WT, const float* avs, const float* avd,
    ushort_t* h, float* s_src, float* s_dst, float* sred,
    int bm, int M, int tid, int wid, int lane, int wr, int wc, int lm, int lk, int lr4){
  for (int hb=0; hb<4; hb++){
    __syncthreads();                           // prior LB/sred readers done
    stage_w128(WT + (size_t)hb*16384, LB, tid);
    __syncthreads();
    floatx4 acc[4][4]; zero_acc(acc);
    ldsgemm<128,128,4>(LA_xb, LB, acc, wr, wc, lm, lk);
    #pragma unroll
    for (int mi=0;mi<4;mi++){
      #pragma unroll
      for (int ni=0;ni<4;ni++){
        int colg = wc + ni*16 + lm;
        #pragma unroll
        for (int r=0;r<4;r++){
          int rowg = bm + wr + mi*16 + lr4 + r;
          if (rowg < M) h[(size_t)rowg*512 + hb*128 + colg] = f2bf(acc[mi][ni][r]);
        }
      }
    }
    sdst_block(acc, avs, avd, s_src, s_dst, sred, hb, bm, M, tid, wid, lane, wr, wc, lm, lr4);
  }
}

// ---------------- k_enc: conv + enc1(relu) + enc2 -> x ; + WGEMM layer0 + SDST ----------------
__global__ __launch_bounds__(256) void k_enc(
    const float* __restrict__ nodef,
    const ushort_t* __restrict__ e1T, const float* __restrict__ eb1,
    const ushort_t* __restrict__ e2T, const float* __restrict__ eb2,
    const ushort_t* __restrict__ WT, const float* __restrict__ avs, const float* __restrict__ avd,
    float* __restrict__ x, ushort_t* __restrict__ h,
    float* __restrict__ s_src, float* __restrict__ s_dst, int M)
{
  __shared__ ushort_t LA[128*128];
  __shared__ ushort_t LB[128*128];
  __shared__ float sred[512];
  const int tid = threadIdx.x, wid = tid>>6, lane = tid&63;
  const int bm = blockIdx.x*128;
  const int wr = (wid>>1)*64, wc = (wid&1)*64, lm = lane&15, lk = (lane>>4)*8, lr4 = (lane>>4)*4;

  // stage node features (f32 -> bf16) into LA
  #pragma unroll
  for (int i=0;i<8;i++){
    int chunk = tid + 256*i;                 // 0..2047, 8 elems each
    int r = chunk>>4, c8 = chunk&15;
    int gr = bm + r; if (gr >= M) gr = M-1;
    floatx4 lo = *(const floatx4*)(nodef + (size_t)gr*128 + c8*8);
    floatx4 hi = *(const floatx4*)(nodef + (size_t)gr*128 + c8*8 + 4);
    ushortx8 v;
    #pragma unroll
    for (int j=0;j<4;j++){ v[j] = f2bf(lo[j]); v[j+4] = f2bf(hi[j]); }
    *(ushortx8*)&LA[r*128 + c8*8] = v;
  }
  stage_w128(e1T, LB, tid);
  __syncthreads();

  floatx4 acc[4][4]; zero_acc(acc);
  ldsgemm<128,128,4>(LA, LB, acc, wr, wc, lm, lk);
  __syncthreads();                           // all LA/LB reads done
  // t1 = relu(acc + eb1) -> LA
  #pragma unroll
  for (int mi=0;mi<4;mi++)
    #pragma unroll
    for (int ni=0;ni<4;ni++){
      int cl = wc + ni*16 + lm;
      float b = eb1[cl];
      #pragma unroll
      for (int r=0;r<4;r++){
        float v = acc[mi][ni][r] + b;
        v = v > 0.f ? v : 0.f;
        LA[(wr + mi*16 + lr4 + r)*128 + cl] = f2bf(v);
      }
    }
  stage_w128(e2T, LB, tid);
  __syncthreads();

  zero_acc(acc);
  ldsgemm<128,128,4>(LA, LB, acc, wr, wc, lm, lk);
  __syncthreads();
  // x = acc + eb2 -> global f32 + LA bf16
  #pragma unroll
  for (int mi=0;mi<4;mi++)
    #pragma unroll
    for (int ni=0;ni<4;ni++){
      int cl = wc + ni*16 + lm;
      float b = eb2[cl];
      #pragma unroll
      for (int r=0;r<4;r++){
        int rl = wr + mi*16 + lr4 + r;
        int rowg = bm + rl;
        float v = acc[mi][ni][r] + b;
        if (rowg < M) x[(size_t)rowg*128 + cl] = v;
        LA[rl*128 + cl] = f2bf(v);
      }
    }

  wgemm_heads(LA, LB, WT, avs, avd, h, s_src, s_dst, sred,
              bm, M, tid, wid, lane, wr, wc, lm, lk, lr4);
}

// ---------------- k_mid: out-proj + bias + resid -> x ; + next WGEMM + SDST ----------------
__global__ __launch_bounds__(256) void k_mid(
    const ushort_t* __restrict__ msg, const ushort_t* __restrict__ OT, const float* __restrict__ ob,
    const ushort_t* __restrict__ WT, const float* __restrict__ avs, const float* __restrict__ avd,
    float* __restrict__ x, ushort_t* __restrict__ h,
    float* __restrict__ s_src, float* __restrict__ s_dst, int M)
{
  __shared__ ushort_t LA[128*128];
  __shared__ ushort_t LB[128*128];
  __shared__ float sred[512];
  const int tid = threadIdx.x, wid = tid>>6, lane = tid&63;
  const int bm = blockIdx.x*128;
  const int wr = (wid>>1)*64, wc = (wid&1)*64, lm = lane&15, lk = (lane>>4)*8, lr4 = (lane>>4)*4;

  floatx4 acc[4][4]; zero_acc(acc);
  for (int kc = 0; kc < 512; kc += 128){      // 4 phases (was 8 at kc step 64)
    stage_tile128(msg, 512, bm, M, kc, LA, tid);
    stage_tile128(OT,  512, 0, 128, kc, LB, tid);
    __syncthreads();
    ldsgemm<128,128,4>(LA, LB, acc, wr, wc, lm, lk);
    __syncthreads();
  }
  // x_new = acc + ob + x_old -> global f32 + LA bf16
  #pragma unroll
  for (int mi=0;mi<4;mi++)
    #pragma unroll
    for (int ni=0;ni<4;ni++){
      int cl = wc + ni*16 + lm;
      float b = ob[cl];
      #pragma unroll
      for (int r=0;r<4;r++){
        int rl = wr + mi*16 + lr4 + r;
        int rowg = bm + rl;
        float v = acc[mi][ni][r] + b;
        if (rowg < M){
          v += x[(size_t)rowg*128 + cl];
          x[(size_t)rowg*128 + cl] = v;
        }
        LA[rl*128 + cl] = f2bf(v);
      }
    }

  wgemm_heads(LA, LB, WT, avs, avd, h, s_src, s_dst, sred,
              bm, M, tid, wid, lane, wr, wc, lm, lk, lr4);
}

// ---------------- k_tail: out-proj3 + resid -> MLP1(relu) -> MLP2 -> d_out + colsum ----------------
__global__ __launch_bounds__(256) void k_tail(
    const ushort_t* __restrict__ msg, const ushort_t* __restrict__ OT, const float* __restrict__ ob,
    const ushort_t* __restrict__ m1T, const float* __restrict__ mb1,
    const ushort_t* __restrict__ m2T, const float* __restrict__ mb2,
    const float* __restrict__ x, float* __restrict__ out, float* __restrict__ cpart, int M)
{
  __shared__ ushort_t LA[128*128];
  __shared__ ushort_t LB[128*128];
  __shared__ float sredc[256];
  const int tid = threadIdx.x, wid = tid>>6, lane = tid&63;
  const int bm = blockIdx.x*128;
  const int wr = (wid>>1)*64, wc = (wid&1)*64, lm = lane&15, lk = (lane>>4)*8, lr4 = (lane>>4)*4;

  floatx4 acc[4][4]; zero_acc(acc);
  for (int kc = 0; kc < 512; kc += 128){      // 4 phases (was 8)
    stage_tile128(msg, 512, bm, M, kc, LA, tid);
    stage_tile128(OT,  512, 0, 128, kc, LB, tid);
    __syncthreads();
    ldsgemm<128,128,4>(LA, LB, acc, wr, wc, lm, lk);
    __syncthreads();
  }
  // x3 = acc + ob + x_old -> LA bf16 (not written globally)
  #pragma unroll
  for (int mi=0;mi<4;mi++)
    #pragma unroll
    for (int ni=0;ni<4;ni++){
      int cl = wc + ni*16 + lm;
      float b = ob[cl];
      #pragma unroll
      for (int r=0;r<4;r++){
        int rl = wr + mi*16 + lr4 + r;
        int rowg = bm + rl;
        float v = acc[mi][ni][r] + b;
        if (rowg < M) v += x[(size_t)rowg*128 + cl];
        LA[rl*128 + cl] = f2bf(v);
      }
    }
  stage_w128(m1T, LB, tid);
  __syncthreads();

  zero_acc(acc);
  ldsgemm<128,128,4>(LA, LB, acc, wr, wc, lm, lk);
  __syncthreads();
  // t = relu(acc + mb1) -> LA
  #pragma unroll
  for (int mi=0;mi<4;mi++)
    #pragma unroll
    for (int ni=0;ni<4;ni++){
      int cl = wc + ni*16 + lm;
      float b = mb1[cl];
      #pragma unroll
      for (int r=0;r<4;r++){
        float v = acc[mi][ni][r] + b;
        v = v > 0.f ? v : 0.f;
        LA[(wr + mi*16 + lr4 + r)*128 + cl] = f2bf(v);
      }
    }
  stage_w128(m2T, LB, tid);
  __syncthreads();

  zero_acc(acc);
  ldsgemm<128,128,4>(LA, LB, acc, wr, wc, lm, lk);

  float csum[4];
  #pragma unroll
  for (int i=0;i<4;i++) csum[i] = 0.f;
  #pragma unroll
  for (int mi=0;mi<4;mi++)
    #pragma unroll
    for (int ni=0;ni<4;ni++){
      int cl = wc + ni*16 + lm;
      float b = mb2[cl];
      #pragma unroll
      for (int r=0;r<4;r++){
        int rowg = bm + wr + mi*16 + lr4 + r;
        if (rowg < M){
          float v = acc[mi][ni][r] + b;
          out[(size_t)rowg*128 + cl] = v;
          csum[ni] += v;
        }
      }
    }
  __syncthreads();                 // LA/LB reads done; reuse sredc
  #pragma unroll
  for (int ni=0;ni<4;ni++){
    float cs = csum[ni];
    cs += __shfl_xor(cs, 16);
    cs += __shfl_xor(cs, 32);
    if (lane < 16) sredc[(wid>>1)*128 + wc + ni*16 + lane] = cs;
  }
  __syncthreads();
  if (tid < 128) cpart[(size_t)blockIdx.x*128 + tid] = sredc[tid] + sredc[128 + tid];
}

// ---------------- fused attention gather (round-5 structure) ----------------
__global__ __launch_bounds__(256) void k_gather(const ushort_t* __restrict__ h,
    const float* __restrict__ s_src, const float* __restrict__ s_dst,
    const int* __restrict__ offs, const int* __restrict__ rowS,
    ushort_t* __restrict__ msg, int N)
{
  int wid = threadIdx.x >> 6, lane = threadIdx.x & 63;
  int n = blockIdx.x*4 + wid;
  if (n >= N) return;
  int beg = offs[n], end = offs[n+1];
  const int sub  = lane & 15;
  const int head = lane >> 4;
  const float sdv = s_dst[(size_t)n*4 + head];
  const int c0 = lane*8;

  float acc[8];
  #pragma unroll
  for (int k=0;k<8;k++) acc[k] = 0.f;
  float dsum = 0.f;

  for (int chunk = beg; chunk < end; chunk += 16){
    int m = end - chunk; if (m > 16) m = 16;
    int q = chunk + (sub < m ? sub : m-1);
    int r_p = rowS[q];
    float ss = s_src[(size_t)r_p*4 + head];
    float e = ss + sdv;
    e = e > 0.f ? e : 0.2f*e;
    float w = __expf(e);
    if (sub >= m) w = 0.f;
    dsum += w;

    int j = 0;
    for (; j+1 < m; j += 2){
      int r0 = __shfl(r_p, j);
      int r1 = __shfl(r_p, j+1);
      float w0 = __shfl(w, head*16 + j);
      float w1 = __shfl(w, head*16 + j+1);
      ushortx8 h0 = *(const ushortx8*)(h + (size_t)r0*512 + c0);
      ushortx8 h1 = *(const ushortx8*)(h + (size_t)r1*512 + c0);
      #pragma unroll
      for (int k=0;k<8;k++) acc[k] += w0 * bf2f(h0[k]);
      #pragma unroll
      for (int k=0;k<8;k++) acc[k] += w1 * bf2f(h1[k]);
    }
    if (j < m){
      int r0 = __shfl(r_p, j);
      float w0 = __shfl(w, head*16 + j);
      ushortx8 h0 = *(const ushortx8*)(h + (size_t)r0*512 + c0);
      #pragma unroll
      for (int k=0;k<8;k++) acc[k] += w0 * bf2f(h0[k]);
    }
  }

  float d = dsum;
  #pragma unroll
  for (int mask=1; mask<16; mask<<=1) d += __shfl_xor(d, mask);
  float invd = 1.0f / (d + 1e-8f);

  ushortx8 o;
  #pragma unroll
  for (int k=0;k<8;k++) o[k] = f2bf(acc[k]*invd);
  __builtin_nontemporal_store(o, (ushortx8*)(msg + (size_t)n*512 + c0));
}

// ---------------- reduce per-block column partials -> mean ----------------
__global__ __launch_bounds__(256) void k_csum2(const float* __restrict__ part, float* __restrict__ out,
                                               int nb, int N){
  __shared__ float buf[256];
  int c = threadIdx.x & 127, half = threadIdx.x >> 7;
  float s = 0.f;
  for (int b = half; b < nb; b += 2) s += part[(size_t)b*128 + c];
  buf[threadIdx.x] = s; __syncthreads();
  if (threadIdx.x < 128) out[c] = (buf[c] + buf[128 + c]) / (float)N;
}

extern "C" void kernel_launch(void* const* d_in, const int* in_sizes, int n_in,
                              void* d_out, int out_size, void* d_ws, size_t ws_size,
                              hipStream_t stream)
{
  const int N = in_sizes[0] / 128;
  const int E = in_sizes[1] / 2;

  const float* nodef  = (const float*)d_in[0];
  const int*   row    = (const int*)d_in[1];
  const int*   col    = row + E;
  const float* enc_w1 = (const float*)d_in[2];
  const float* enc_b1 = (const float*)d_in[3];
  const float* enc_w2 = (const float*)d_in[4];
  const float* enc_b2 = (const float*)d_in[5];
  const float* gat_W  = (const float*)d_in[6];
  const float* a_src  = (const float*)d_in[7];
  const float* a_dst  = (const float*)d_in[8];
  const float* out_w  = (const float*)d_in[9];
  const float* out_b  = (const float*)d_in[10];
  const float* w1     = (const float*)d_in[11];
  const float* b1     = (const float*)d_in[12];
  const float* w2     = (const float*)d_in[13];
  const float* b2     = (const float*)d_in[14];

  char* p = (char*)d_ws;
  auto alloc = [&](size_t bytes)->char*{
    char* r = p; p += (bytes + 255) & ~(size_t)255; return r;
  };
  float*    x     = (float*)   alloc((size_t)N*128*4);
  ushort_t* msg   = (ushort_t*)alloc((size_t)N*512*2);
  ushort_t* h     = (ushort_t*)alloc((size_t)N*512*2);
  float*    s_src = (float*)   alloc((size_t)N*4*4);
  float*    s_dst = (float*)   alloc((size_t)N*4*4);
  int*      offs  = (int*)     alloc(((size_t)N+1)*4);
  int*      rowS  = (int*)     alloc((size_t)E*4);
  int*      cnt   = (int*)     alloc((size_t)N*4);
  int*      fill  = (int*)     alloc((size_t)N*4);
  int*      parts = (int*)     alloc(1024);
  float*    cpart = (float*)   alloc((size_t)((N+127)/128)*128*4);
  ushort_t* wt_e1 = (ushort_t*)alloc(16384*2);
  ushort_t* wt_e2 = (ushort_t*)alloc(16384*2);
  ushort_t* wt_W  = (ushort_t*)alloc((size_t)3*65536*2);
  ushort_t* wt_o  = (ushort_t*)alloc((size_t)3*65536*2);
  ushort_t* wt_m1 = (ushort_t*)alloc(16384*2);
  ushort_t* wt_m2 = (ushort_t*)alloc(16384*2);

  hipMemsetAsync(cnt, 0, (size_t)N*4, stream);
  hipMemsetAsync(fill, 0, (size_t)N*4, stream);

  const int gE = (E + 255)/256;
  const int gN = (N + 255)/256;
  const int gW = (N + 3)/4;
  const int gy = (N + 127)/128;
  dim3 blk(256);

  // CSR by destination
  k_count<<<gE, blk, 0, stream>>>(col, cnt, E);
  k_scan1<<<gN, blk, 0, stream>>>(cnt, offs, parts, N);
  k_scan2<<<1,  blk, 0, stream>>>(parts, gN);
  k_scan3<<<gN, blk, 0, stream>>>(offs, parts, N, E);
  k_fill <<<gE, blk, 0, stream>>>(row, col, offs, fill, rowS, E);

  // weight conversion (bf16, transposed to [NC,K])
  k_convT4<<<(4*16384+255)/256, blk, 0, stream>>>(enc_w1, enc_w2, w1, w2, wt_e1, wt_e2, wt_m1, wt_m2);
  k_convT_b<128,512,3><<<(3*65536+255)/256, blk, 0, stream>>>(gat_W, wt_W);
  k_convT_b<512,128,3><<<(3*65536+255)/256, blk, 0, stream>>>(out_w, wt_o);

  // encoder + layer-0 W-GEMM + SDST
  k_enc<<<gy, blk, 0, stream>>>(nodef, wt_e1, enc_b1, wt_e2, enc_b2,
                                wt_W, a_src, a_dst, x, h, s_src, s_dst, N);

  for (int l = 0; l < 3; l++){
    k_gather<<<gW, blk, 0, stream>>>(h, s_src, s_dst, offs, rowS, msg, N);
    if (l < 2){
      k_mid<<<gy, blk, 0, stream>>>(msg, wt_o + (size_t)l*65536, out_b + (size_t)l*128,
                                    wt_W + (size_t)(l+1)*65536,
                                    a_src + (size_t)(l+1)*512, a_dst + (size_t)(l+1)*512,
                                    x, h, s_src, s_dst, N);
    } else {
      k_tail<<<gy, blk, 0, stream>>>(msg, wt_o + (size_t)2*65536, out_b + (size_t)2*128,
                                     wt_m1, b1, wt_m2, b2,
                                     x, (float*)d_out, cpart, N);
    }
  }
  k_csum2<<<1, blk, 0, stream>>>(cpart, (float*)d_out + (size_t)N*128, gy, N);
}

// Round 10
// 511.049 us; speedup vs baseline: 1.3112x; 1.0863x over previous
//
#include <hip/hip_runtime.h>
#include <math.h>

typedef unsigned short ushort_t;
typedef __attribute__((ext_vector_type(8))) unsigned short ushortx8;
typedef __attribute__((ext_vector_type(4))) unsigned short ushortx4;
typedef __attribute__((ext_vector_type(4))) float floatx4;
typedef __attribute__((ext_vector_type(8))) short frag8;   // MFMA A/B operand (8 bf16)

__device__ __forceinline__ float bf2f(ushort_t u){
  union {unsigned int i; float f;} v; v.i = ((unsigned int)u)<<16; return v.f;
}
__device__ __forceinline__ ushort_t f2bf(float f){
  union {float f; unsigned int i;} v; v.f = f;
  unsigned int x = v.i;
  unsigned int r = x + 0x7fffu + ((x>>16)&1u);
  return (ushort_t)(r>>16);
}

__device__ __forceinline__ void gload16(const void* g, void* l){
  __builtin_amdgcn_global_load_lds(
      (const __attribute__((address_space(1))) unsigned int*)g,
      (__attribute__((address_space(3))) unsigned int*)l, 16, 0, 0);
}

// ---------------- CSR build ----------------
__global__ __launch_bounds__(256) void k_count(const int* __restrict__ col, int* __restrict__ cnt, int E){
  int e = blockIdx.x*256 + threadIdx.x;
  if (e < E) atomicAdd(&cnt[col[e]], 1);
}

__global__ __launch_bounds__(256) void k_scan1(const int* __restrict__ cnt, int* __restrict__ offs,
                                               int* __restrict__ partials, int n){
  __shared__ int buf[256];
  int tid = threadIdx.x;
  int gid = blockIdx.x*256 + tid;
  int v = (gid < n) ? cnt[gid] : 0;
  buf[tid] = v; __syncthreads();
  #pragma unroll
  for (int off=1; off<256; off<<=1){
    int t = (tid >= off) ? buf[tid-off] : 0;
    __syncthreads();
    buf[tid] += t;
    __syncthreads();
  }
  if (gid < n) offs[gid] = buf[tid] - v;
  if (tid == 255) partials[blockIdx.x] = buf[255];
}

__global__ __launch_bounds__(256) void k_scan2(int* __restrict__ partials, int nb){
  __shared__ int buf[256];
  int tid = threadIdx.x;
  int v = (tid < nb) ? partials[tid] : 0;
  buf[tid] = v; __syncthreads();
  #pragma unroll
  for (int off=1; off<256; off<<=1){
    int t = (tid >= off) ? buf[tid-off] : 0;
    __syncthreads();
    buf[tid] += t;
    __syncthreads();
  }
  partials[tid] = buf[tid] - v;
}

__global__ __launch_bounds__(256) void k_scan3(int* __restrict__ offs, const int* __restrict__ partials,
                                               int n, int E){
  int gid = blockIdx.x*256 + threadIdx.x;
  if (gid < n) offs[gid] += partials[blockIdx.x];
  if (blockIdx.x == 0 && threadIdx.x == 0) offs[n] = E;
}

__global__ __launch_bounds__(256) void k_fill(const int* __restrict__ row, const int* __restrict__ col,
                                              const int* __restrict__ offs, int* __restrict__ fill,
                                              int* __restrict__ rowS, int E){
  int e = blockIdx.x*256 + threadIdx.x;
  if (e >= E) return;
  int c = col[e];
  int pos = offs[c] + atomicAdd(&fill[c], 1);
  rowS[pos] = row[e];
}

// ---------------- weight conversions ----------------
template<int K, int NC, int CNT>
__global__ __launch_bounds__(256) void k_convT_b(const float* __restrict__ src, ushort_t* __restrict__ dst){
  int idx = blockIdx.x*256 + threadIdx.x;
  if (idx >= CNT*K*NC) return;
  int l = idx / (K*NC);
  int rem = idx - l*(K*NC);
  int k = rem / NC, n = rem - k*NC;
  dst[(size_t)l*K*NC + (size_t)n*K + k] = f2bf(src[idx]);
}

__global__ __launch_bounds__(256) void k_convT4(const float* __restrict__ s0, const float* __restrict__ s1,
                                                const float* __restrict__ s2, const float* __restrict__ s3,
                                                ushort_t* __restrict__ d0, ushort_t* __restrict__ d1,
                                                ushort_t* __restrict__ d2, ushort_t* __restrict__ d3){
  int idx = blockIdx.x*256 + threadIdx.x;
  if (idx >= 4*16384) return;
  int which = idx >> 14;
  int rem = idx & 16383;
  int k = rem >> 7, n = rem & 127;
  const float* s = which==0 ? s0 : which==1 ? s1 : which==2 ? s2 : s3;
  ushort_t*    d = which==0 ? d0 : which==1 ? d1 : which==2 ? d2 : d3;
  d[n*128 + k] = f2bf(s[rem]);
}

// ---------------- fused-kernel building blocks (round-6 structure, TRANSPOSED mfma) ----------------
// mfma(b, a) computes C^T: lane (lm=lane&15, hi=lane>>4) holds
//   C[row = tileR + lm][col = tileC + hi*4 + r], r = 0..3.
// -> epilogues are column-vectorized: floatx4 / ushortx4 per lane.

// stage a [128 rows][64 k] bf16 tile from row-major global (ld elems) into lds (stride 64)
__device__ __forceinline__ void stage_tile64(const ushort_t* src, int ld, int row0, int M, int kc,
                                             ushort_t* lds, int tid){
  int wid = tid>>6, lane = tid&63;
  #pragma unroll
  for (int i=0;i<4;i++){
    int chunk = wid*256 + i*64 + lane;   // 0..1023 (16B chunks)
    int r = chunk>>3, c8 = chunk&7;
    int gr = row0 + r; if (gr >= M) gr = M-1;
    gload16(src + (size_t)gr*ld + kc + c8*8, (char*)lds + (size_t)chunk*16);
  }
}
// stage a full contiguous [128][128] bf16 weight block into lds (stride 128)
__device__ __forceinline__ void stage_w128(const ushort_t* src, ushort_t* lds, int tid){
  #pragma unroll
  for (int i=0;i<8;i++){
    int chunk = tid + 256*i;             // 0..2047
    gload16(src + (size_t)chunk*8, (char*)lds + (size_t)chunk*16);
  }
}

// GEMM on LDS tiles: acc(C^T frag) += LA[128xK] * LB[128xK]^T  (strides SA/SB, K = NKS*32)
template<int SA,int SB,int NKS>
__device__ __forceinline__ void ldsgemm(const ushort_t* LA, const ushort_t* LB,
                                        floatx4 (&acc)[4][4], int wr,int wc,int lm,int lk){
  #pragma unroll
  for (int ks=0; ks<NKS; ks++){
    frag8 a[4], b[4];
    #pragma unroll
    for (int mi=0;mi<4;mi++) a[mi] = *(const frag8*)&LA[(wr+mi*16+lm)*SA + ks*32 + lk];
    #pragma unroll
    for (int ni=0;ni<4;ni++) b[ni] = *(const frag8*)&LB[(wc+ni*16+lm)*SB + ks*32 + lk];
    #pragma unroll
    for (int mi=0;mi<4;mi++)
      #pragma unroll
      for (int ni=0;ni<4;ni++)
        acc[mi][ni] = __builtin_amdgcn_mfma_f32_16x16x32_bf16(b[ni], a[mi], acc[mi][ni], 0, 0, 0);
  }
}

__device__ __forceinline__ void zero_acc(floatx4 (&acc)[4][4]){
  #pragma unroll
  for (int i=0;i<4;i++)
    #pragma unroll
    for (int j=0;j<4;j++) acc[i][j] = floatx4{0.f,0.f,0.f,0.f};
}

// s_src/s_dst for one head (transposed acc: lane holds cols lr4+r of row lm)
__device__ __forceinline__ void sdst_block(const floatx4 (&acc)[4][4],
    const float* avec_s, const float* avec_d, float* s_src, float* s_dst, float* sred,
    int head, int bm, int M, int tid, int wid, int lane, int wr, int wc, int lm, int lr4){
  floatx4 avs[4], avd[4];
  #pragma unroll
  for (int ni=0;ni<4;ni++){
    avs[ni] = *(const floatx4*)&avec_s[head*128 + wc + ni*16 + lr4];
    avd[ni] = *(const floatx4*)&avec_d[head*128 + wc + ni*16 + lr4];
  }
  #pragma unroll
  for (int mi=0;mi<4;mi++){
    float vs = 0.f, vd = 0.f;
    #pragma unroll
    for (int ni=0;ni<4;ni++)
      #pragma unroll
      for (int r=0;r<4;r++){
        float v = acc[mi][ni][r];
        vs += v * avs[ni][r];
        vd += v * avd[ni][r];
      }
    vs += __shfl_xor(vs, 16); vs += __shfl_xor(vs, 32);
    vd += __shfl_xor(vd, 16); vd += __shfl_xor(vd, 32);
    if (lane < 16){                      // hi == 0
      int rl = wr + mi*16 + lm;
      sred[0*256 + (wid&1)*128 + rl] = vs;
      sred[1*256 + (wid&1)*128 + rl] = vd;
    }
  }
  __syncthreads();
  int sd = tid >> 7, rl = tid & 127;
  float v = sred[sd*256 + rl] + sred[sd*256 + 128 + rl];
  int rowg = bm + rl;
  if (rowg < M) (sd ? s_dst : s_src)[(size_t)rowg*4 + head] = v;
}

// per-head W-GEMM + vectorized h write + SDST.  LA preserved, LB clobbered.
__device__ __forceinline__ void wgemm_heads(const ushort_t* LA_xb, ushort_t* LB,
    const ushort_t* WT, const float* avs, const float* avd,
    ushort_t* h, float* s_src, float* s_dst, float* sred,
    int bm, int M, int tid, int wid, int lane, int wr, int wc, int lm, int lk, int lr4){
  for (int hb=0; hb<4; hb++){
    __syncthreads();                           // prior LB/sred readers done
    stage_w128(WT + (size_t)hb*16384, LB, tid);
    __syncthreads();
    floatx4 acc[4][4]; zero_acc(acc);
    ldsgemm<128,128,4>(LA_xb, LB, acc, wr, wc, lm, lk);
    #pragma unroll
    for (int mi=0;mi<4;mi++){
      int rowg = bm + wr + mi*16 + lm;
      if (rowg < M){
        #pragma unroll
        for (int ni=0;ni<4;ni++){
          int coll = wc + ni*16 + lr4;
          ushortx4 o;
          #pragma unroll
          for (int r=0;r<4;r++) o[r] = f2bf(acc[mi][ni][r]);
          *(ushortx4*)&h[(size_t)rowg*512 + hb*128 + coll] = o;
        }
      }
    }
    sdst_block(acc, avs, avd, s_src, s_dst, sred, hb, bm, M, tid, wid, lane, wr, wc, lm, lr4);
  }
}

// ---------------- k_enc: conv + enc1(relu) + enc2 -> x ; + WGEMM layer0 + SDST ----------------
__global__ __launch_bounds__(256) void k_enc(
    const float* __restrict__ nodef,
    const ushort_t* __restrict__ e1T, const float* __restrict__ eb1,
    const ushort_t* __restrict__ e2T, const float* __restrict__ eb2,
    const ushort_t* __restrict__ WT, const float* __restrict__ avs, const float* __restrict__ avd,
    float* __restrict__ x, ushort_t* __restrict__ h,
    float* __restrict__ s_src, float* __restrict__ s_dst, int M)
{
  __shared__ ushort_t LA[128*128];
  __shared__ ushort_t LB[128*128];
  __shared__ float sred[512];
  const int tid = threadIdx.x, wid = tid>>6, lane = tid&63;
  const int bm = blockIdx.x*128;
  const int wr = (wid>>1)*64, wc = (wid&1)*64, lm = lane&15, lk = (lane>>4)*8, lr4 = (lane>>4)*4;

  // stage node features (f32 -> bf16) into LA
  #pragma unroll
  for (int i=0;i<8;i++){
    int chunk = tid + 256*i;                 // 0..2047, 8 elems each
    int r = chunk>>4, c8 = chunk&15;
    int gr = bm + r; if (gr >= M) gr = M-1;
    floatx4 lo = *(const floatx4*)(nodef + (size_t)gr*128 + c8*8);
    floatx4 hi = *(const floatx4*)(nodef + (size_t)gr*128 + c8*8 + 4);
    ushortx8 v;
    #pragma unroll
    for (int j=0;j<4;j++){ v[j] = f2bf(lo[j]); v[j+4] = f2bf(hi[j]); }
    *(ushortx8*)&LA[r*128 + c8*8] = v;
  }
  stage_w128(e1T, LB, tid);
  __syncthreads();

  floatx4 acc[4][4]; zero_acc(acc);
  ldsgemm<128,128,4>(LA, LB, acc, wr, wc, lm, lk);
  __syncthreads();                           // all LA/LB reads done
  // t1 = relu(acc + eb1) -> LA (transposed frag: 8B stores)
  #pragma unroll
  for (int mi=0;mi<4;mi++){
    int rl = wr + mi*16 + lm;
    #pragma unroll
    for (int ni=0;ni<4;ni++){
      int coll = wc + ni*16 + lr4;
      floatx4 b4 = *(const floatx4*)&eb1[coll];
      ushortx4 o;
      #pragma unroll
      for (int r=0;r<4;r++){
        float v = acc[mi][ni][r] + b4[r];
        v = v > 0.f ? v : 0.f;
        o[r] = f2bf(v);
      }
      *(ushortx4*)&LA[rl*128 + coll] = o;
    }
  }
  stage_w128(e2T, LB, tid);
  __syncthreads();

  zero_acc(acc);
  ldsgemm<128,128,4>(LA, LB, acc, wr, wc, lm, lk);
  __syncthreads();
  // x = acc + eb2 -> global f32 (16B) + LA bf16 (8B)
  #pragma unroll
  for (int mi=0;mi<4;mi++){
    int rl = wr + mi*16 + lm;
    int rowg = bm + rl;
    #pragma unroll
    for (int ni=0;ni<4;ni++){
      int coll = wc + ni*16 + lr4;
      floatx4 b4 = *(const floatx4*)&eb2[coll];
      floatx4 v;
      #pragma unroll
      for (int r=0;r<4;r++) v[r] = acc[mi][ni][r] + b4[r];
      if (rowg < M) *(floatx4*)&x[(size_t)rowg*128 + coll] = v;
      ushortx4 o;
      #pragma unroll
      for (int r=0;r<4;r++) o[r] = f2bf(v[r]);
      *(ushortx4*)&LA[rl*128 + coll] = o;
    }
  }

  wgemm_heads(LA, LB, WT, avs, avd, h, s_src, s_dst, sred,
              bm, M, tid, wid, lane, wr, wc, lm, lk, lr4);
}

// ---------------- k_mid: out-proj + bias + resid -> x ; + next WGEMM + SDST ----------------
__global__ __launch_bounds__(256) void k_mid(
    const ushort_t* __restrict__ msg, const ushort_t* __restrict__ OT, const float* __restrict__ ob,
    const ushort_t* __restrict__ WT, const float* __restrict__ avs, const float* __restrict__ avd,
    float* __restrict__ x, ushort_t* __restrict__ h,
    float* __restrict__ s_src, float* __restrict__ s_dst, int M)
{
  __shared__ ushort_t LA[128*128];
  __shared__ ushort_t LB[128*128];
  __shared__ float sred[512];
  const int tid = threadIdx.x, wid = tid>>6, lane = tid&63;
  const int bm = blockIdx.x*128;
  const int wr = (wid>>1)*64, wc = (wid&1)*64, lm = lane&15, lk = (lane>>4)*8, lr4 = (lane>>4)*4;

  floatx4 acc[4][4]; zero_acc(acc);
  for (int kc = 0; kc < 512; kc += 64){
    stage_tile64(msg, 512, bm, M, kc, LA, tid);
    stage_tile64(OT,  512, 0, 128, kc, LB, tid);
    __syncthreads();
    ldsgemm<64,64,2>(LA, LB, acc, wr, wc, lm, lk);
    __syncthreads();
  }
  // x_new = acc + ob + x_old -> global f32 (16B) + LA bf16 (8B)
  #pragma unroll
  for (int mi=0;mi<4;mi++){
    int rl = wr + mi*16 + lm;
    int rowg = bm + rl;
    #pragma unroll
    for (int ni=0;ni<4;ni++){
      int coll = wc + ni*16 + lr4;
      floatx4 b4 = *(const floatx4*)&ob[coll];
      floatx4 v;
      #pragma unroll
      for (int r=0;r<4;r++) v[r] = acc[mi][ni][r] + b4[r];
      if (rowg < M){
        floatx4 xo = *(const floatx4*)&x[(size_t)rowg*128 + coll];
        #pragma unroll
        for (int r=0;r<4;r++) v[r] += xo[r];
        *(floatx4*)&x[(size_t)rowg*128 + coll] = v;
      }
      ushortx4 o;
      #pragma unroll
      for (int r=0;r<4;r++) o[r] = f2bf(v[r]);
      *(ushortx4*)&LA[rl*128 + coll] = o;
    }
  }

  wgemm_heads(LA, LB, WT, avs, avd, h, s_src, s_dst, sred,
              bm, M, tid, wid, lane, wr, wc, lm, lk, lr4);
}

// ---------------- k_tail: out-proj3 + resid -> MLP1(relu) -> MLP2 -> d_out + colsum ----------------
__global__ __launch_bounds__(256) void k_tail(
    const ushort_t* __restrict__ msg, const ushort_t* __restrict__ OT, const float* __restrict__ ob,
    const ushort_t* __restrict__ m1T, const float* __restrict__ mb1,
    const ushort_t* __restrict__ m2T, const float* __restrict__ mb2,
    const float* __restrict__ x, float* __restrict__ out, float* __restrict__ cpart, int M)
{
  __shared__ ushort_t LA[128*128];
  __shared__ ushort_t LB[128*128];
  __shared__ float sredc[256];
  const int tid = threadIdx.x, wid = tid>>6, lane = tid&63;
  const int bm = blockIdx.x*128;
  const int wr = (wid>>1)*64, wc = (wid&1)*64, lm = lane&15, lk = (lane>>4)*8, lr4 = (lane>>4)*4;

  floatx4 acc[4][4]; zero_acc(acc);
  for (int kc = 0; kc < 512; kc += 64){
    stage_tile64(msg, 512, bm, M, kc, LA, tid);
    stage_tile64(OT,  512, 0, 128, kc, LB, tid);
    __syncthreads();
    ldsgemm<64,64,2>(LA, LB, acc, wr, wc, lm, lk);
    __syncthreads();
  }
  // x3 = acc + ob + x_old -> LA bf16
  #pragma unroll
  for (int mi=0;mi<4;mi++){
    int rl = wr + mi*16 + lm;
    int rowg = bm + rl;
    #pragma unroll
    for (int ni=0;ni<4;ni++){
      int coll = wc + ni*16 + lr4;
      floatx4 b4 = *(const floatx4*)&ob[coll];
      floatx4 v;
      #pragma unroll
      for (int r=0;r<4;r++) v[r] = acc[mi][ni][r] + b4[r];
      if (rowg < M){
        floatx4 xo = *(const floatx4*)&x[(size_t)rowg*128 + coll];
        #pragma unroll
        for (int r=0;r<4;r++) v[r] += xo[r];
      }
      ushortx4 o;
      #pragma unroll
      for (int r=0;r<4;r++) o[r] = f2bf(v[r]);
      *(ushortx4*)&LA[rl*128 + coll] = o;
    }
  }
  stage_w128(m1T, LB, tid);
  __syncthreads();

  zero_acc(acc);
  ldsgemm<128,128,4>(LA, LB, acc, wr, wc, lm, lk);
  __syncthreads();
  // t = relu(acc + mb1) -> LA
  #pragma unroll
  for (int mi=0;mi<4;mi++){
    int rl = wr + mi*16 + lm;
    #pragma unroll
    for (int ni=0;ni<4;ni++){
      int coll = wc + ni*16 + lr4;
      floatx4 b4 = *(const floatx4*)&mb1[coll];
      ushortx4 o;
      #pragma unroll
      for (int r=0;r<4;r++){
        float v = acc[mi][ni][r] + b4[r];
        v = v > 0.f ? v : 0.f;
        o[r] = f2bf(v);
      }
      *(ushortx4*)&LA[rl*128 + coll] = o;
    }
  }
  stage_w128(m2T, LB, tid);
  __syncthreads();

  zero_acc(acc);
  ldsgemm<128,128,4>(LA, LB, acc, wr, wc, lm, lk);

  float csum[4][4];
  #pragma unroll
  for (int i=0;i<4;i++)
    #pragma unroll
    for (int r=0;r<4;r++) csum[i][r] = 0.f;
  #pragma unroll
  for (int mi=0;mi<4;mi++){
    int rowg = bm + wr + mi*16 + lm;
    #pragma unroll
    for (int ni=0;ni<4;ni++){
      int coll = wc + ni*16 + lr4;
      floatx4 b4 = *(const floatx4*)&mb2[coll];
      floatx4 v;
      #pragma unroll
      for (int r=0;r<4;r++) v[r] = acc[mi][ni][r] + b4[r];
      if (rowg < M){
        *(floatx4*)&out[(size_t)rowg*128 + coll] = v;
        #pragma unroll
        for (int r=0;r<4;r++) csum[ni][r] += v[r];
      }
    }
  }
  __syncthreads();                 // LA/LB reads done; reuse sredc
  #pragma unroll
  for (int ni=0;ni<4;ni++)
    #pragma unroll
    for (int r=0;r<4;r++){
      float cs = csum[ni][r];
      cs += __shfl_xor(cs, 1);
      cs += __shfl_xor(cs, 2);
      cs += __shfl_xor(cs, 4);
      cs += __shfl_xor(cs, 8);
      if (lm == 0) sredc[(wid>>1)*128 + wc + ni*16 + lr4 + r] = cs;
    }
  __syncthreads();
  if (tid < 128) cpart[(size_t)blockIdx.x*128 + tid] = sredc[tid] + sredc[128 + tid];
}

// ---------------- fused attention gather (round-5 structure) ----------------
__global__ __launch_bounds__(256) void k_gather(const ushort_t* __restrict__ h,
    const float* __restrict__ s_src, const float* __restrict__ s_dst,
    const int* __restrict__ offs, const int* __restrict__ rowS,
    ushort_t* __restrict__ msg, int N)
{
  int wid = threadIdx.x >> 6, lane = threadIdx.x & 63;
  int n = blockIdx.x*4 + wid;
  if (n >= N) return;
  int beg = offs[n], end = offs[n+1];
  const int sub  = lane & 15;
  const int head = lane >> 4;
  const float sdv = s_dst[(size_t)n*4 + head];
  const int c0 = lane*8;

  float acc[8];
  #pragma unroll
  for (int k=0;k<8;k++) acc[k] = 0.f;
  float dsum = 0.f;

  for (int chunk = beg; chunk < end; chunk += 16){
    int m = end - chunk; if (m > 16) m = 16;
    int q = chunk + (sub < m ? sub : m-1);
    int r_p = rowS[q];
    float ss = s_src[(size_t)r_p*4 + head];
    float e = ss + sdv;
    e = e > 0.f ? e : 0.2f*e;
    float w = __expf(e);
    if (sub >= m) w = 0.f;
    dsum += w;

    int j = 0;
    for (; j+1 < m; j += 2){
      int r0 = __shfl(r_p, j);
      int r1 = __shfl(r_p, j+1);
      float w0 = __shfl(w, head*16 + j);
      float w1 = __shfl(w, head*16 + j+1);
      ushortx8 h0 = *(const ushortx8*)(h + (size_t)r0*512 + c0);
      ushortx8 h1 = *(const ushortx8*)(h + (size_t)r1*512 + c0);
      #pragma unroll
      for (int k=0;k<8;k++) acc[k] += w0 * bf2f(h0[k]);
      #pragma unroll
      for (int k=0;k<8;k++) acc[k] += w1 * bf2f(h1[k]);
    }
    if (j < m){
      int r0 = __shfl(r_p, j);
      float w0 = __shfl(w, head*16 + j);
      ushortx8 h0 = *(const ushortx8*)(h + (size_t)r0*512 + c0);
      #pragma unroll
      for (int k=0;k<8;k++) acc[k] += w0 * bf2f(h0[k]);
    }
  }

  float d = dsum;
  #pragma unroll
  for (int mask=1; mask<16; mask<<=1) d += __shfl_xor(d, mask);
  float invd = 1.0f / (d + 1e-8f);

  ushortx8 o;
  #pragma unroll
  for (int k=0;k<8;k++) o[k] = f2bf(acc[k]*invd);
  __builtin_nontemporal_store(o, (ushortx8*)(msg + (size_t)n*512 + c0));
}

// ---------------- reduce per-block column partials -> mean ----------------
__global__ __launch_bounds__(256) void k_csum2(const float* __restrict__ part, float* __restrict__ out,
                                               int nb, int N){
  __shared__ float buf[256];
  int c = threadIdx.x & 127, half = threadIdx.x >> 7;
  float s = 0.f;
  for (int b = half; b < nb; b += 2) s += part[(size_t)b*128 + c];
  buf[threadIdx.x] = s; __syncthreads();
  if (threadIdx.x < 128) out[c] = (buf[c] + buf[128 + c]) / (float)N;
}

extern "C" void kernel_launch(void* const* d_in, const int* in_sizes, int n_in,
                              void* d_out, int out_size, void* d_ws, size_t ws_size,
                              hipStream_t stream)
{
  const int N = in_sizes[0] / 128;
  const int E = in_sizes[1] / 2;

  const float* nodef  = (const float*)d_in[0];
  const int*   row    = (const int*)d_in[1];
  const int*   col    = row + E;
  const float* enc_w1 = (const float*)d_in[2];
  const float* enc_b1 = (const float*)d_in[3];
  const float* enc_w2 = (const float*)d_in[4];
  const float* enc_b2 = (const float*)d_in[5];
  const float* gat_W  = (const float*)d_in[6];
  const float* a_src  = (const float*)d_in[7];
  const float* a_dst  = (const float*)d_in[8];
  const float* out_w  = (const float*)d_in[9];
  const float* out_b  = (const float*)d_in[10];
  const float* w1     = (const float*)d_in[11];
  const float* b1     = (const float*)d_in[12];
  const float* w2     = (const float*)d_in[13];
  const float* b2     = (const float*)d_in[14];

  char* p = (char*)d_ws;
  auto alloc = [&](size_t bytes)->char*{
    char* r = p; p += (bytes + 255) & ~(size_t)255; return r;
  };
  float*    x     = (float*)   alloc((size_t)N*128*4);
  ushort_t* msg   = (ushort_t*)alloc((size_t)N*512*2);
  ushort_t* h     = (ushort_t*)alloc((size_t)N*512*2);
  float*    s_src = (float*)   alloc((size_t)N*4*4);
  float*    s_dst = (float*)   alloc((size_t)N*4*4);
  int*      offs  = (int*)     alloc(((size_t)N+1)*4);
  int*      rowS  = (int*)     alloc((size_t)E*4);
  int*      cnt   = (int*)     alloc((size_t)N*4);
  int*      fill  = (int*)     alloc((size_t)N*4);
  int*      parts = (int*)     alloc(1024);
  float*    cpart = (float*)   alloc((size_t)((N+127)/128)*128*4);
  ushort_t* wt_e1 = (ushort_t*)alloc(16384*2);
  ushort_t* wt_e2 = (ushort_t*)alloc(16384*2);
  ushort_t* wt_W  = (ushort_t*)alloc((size_t)3*65536*2);
  ushort_t* wt_o  = (ushort_t*)alloc((size_t)3*65536*2);
  ushort_t* wt_m1 = (ushort_t*)alloc(16384*2);
  ushort_t* wt_m2 = (ushort_t*)alloc(16384*2);

  hipMemsetAsync(cnt, 0, (size_t)N*4, stream);
  hipMemsetAsync(fill, 0, (size_t)N*4, stream);

  const int gE = (E + 255)/256;
  const int gN = (N + 255)/256;
  const int gW = (N + 3)/4;
  const int gy = (N + 127)/128;
  dim3 blk(256);

  // CSR by destination
  k_count<<<gE, blk, 0, stream>>>(col, cnt, E);
  k_scan1<<<gN, blk, 0, stream>>>(cnt, offs, parts, N);
  k_scan2<<<1,  blk, 0, stream>>>(parts, gN);
  k_scan3<<<gN, blk, 0, stream>>>(offs, parts, N, E);
  k_fill <<<gE, blk, 0, stream>>>(row, col, offs, fill, rowS, E);

  // weight conversion (bf16, transposed to [NC,K])
  k_convT4<<<(4*16384+255)/256, blk, 0, stream>>>(enc_w1, enc_w2, w1, w2, wt_e1, wt_e2, wt_m1, wt_m2);
  k_convT_b<128,512,3><<<(3*65536+255)/256, blk, 0, stream>>>(gat_W, wt_W);
  k_convT_b<512,128,3><<<(3*65536+255)/256, blk, 0, stream>>>(out_w, wt_o);

  // encoder + layer-0 W-GEMM + SDST
  k_enc<<<gy, blk, 0, stream>>>(nodef, wt_e1, enc_b1, wt_e2, enc_b2,
                                wt_W, a_src, a_dst, x, h, s_src, s_dst, N);

  for (int l = 0; l < 3; l++){
    k_gather<<<gW, blk, 0, stream>>>(h, s_src, s_dst, offs, rowS, msg, N);
    if (l < 2){
      k_mid<<<gy, blk, 0, stream>>>(msg, wt_o + (size_t)l*65536, out_b + (size_t)l*128,
                                    wt_W + (size_t)(l+1)*65536,
                                    a_src + (size_t)(l+1)*512, a_dst + (size_t)(l+1)*512,
                                    x, h, s_src, s_dst, N);
    } else {
      k_tail<<<gy, blk, 0, stream>>>(msg, wt_o + (size_t)2*65536, out_b + (size_t)2*128,
                                     wt_m1, b1, wt_m2, b2,
                                     x, (float*)d_out, cpart, N);
    }
  }
  k_csum2<<<1, blk, 0, stream>>>(cpart, (float*)d_out + (size_t)N*128, gy, N);
}